// Round 15
// baseline (42.466 us; speedup 1.0000x reference)
//
#include <hip/hip_runtime.h>
#include <hip/hip_bf16.h>
#include <math.h>

#define BB 4
#define CC 64
#define OCN 64
#define HH 128
#define WW 128
#define HW (HH*WW)
#define KKN 9
#define APAD 200          // accs row stride x2 bytes (400 B) for phase-C tile
#define RSTRIDE 144       // raw-row stride in bytes (64ch*2B + 16B pad)
#define SLOTSZ (66*RSTRIDE)  // 9504 B per raw-row slot

typedef short short8 __attribute__((ext_vector_type(8)));
typedef short short4v __attribute__((ext_vector_type(4)));
typedef float floatx4 __attribute__((ext_vector_type(4)));
typedef float floatx2 __attribute__((ext_vector_type(2)));
typedef unsigned int uintx4 __attribute__((ext_vector_type(4)));

__device__ __forceinline__ float bf2f_us(unsigned short u) {
    return __uint_as_float(((unsigned)u) << 16);
}
__device__ __forceinline__ short f2bfs(float f) {
    __hip_bfloat16 h = __float2bfloat16(f);
    return *reinterpret_cast<short*>(&h);
}
__device__ __forceinline__ uintx4 as_u4(short8 v) {
    union { short8 s; uintx4 u; } x; x.s = v; return x.u;
}
__device__ __forceinline__ float blo(unsigned d) { return __uint_as_float(d << 16); }
__device__ __forceinline__ float bhi(unsigned d) { return __uint_as_float(d & 0xffff0000u); }

// ---------------- transpose_prep: float4 loads, 64 px/block, XOR-swizzled tile (= R13) -
__global__ __launch_bounds__(256) void transpose_prep(
    const float* __restrict__ x,
    const float* __restrict__ w_dcn, const float* __restrict__ w_off,
    const float* __restrict__ b_off, const float* __restrict__ w_mask,
    const float* __restrict__ b_mask,
    __hip_bfloat16* __restrict__ xt, __hip_bfloat16* __restrict__ wTf,
    __hip_bfloat16* __restrict__ wOf, float* __restrict__ rebias)
{
    int blk = blockIdx.x;
    int tid = threadIdx.x;
    if (blk < BB * 256) {
        __shared__ float tile[64][64];   // col = p ^ ((c>>3)<<2), 16 KB
        int pixbase = (blk & 255) * 64;
        int b       = blk >> 8;
        const float* xb = x + (size_t)b * CC * HW;
        #pragma unroll
        for (int i = 0; i < 4; ++i) {
            int c  = (tid >> 4) + i * 16;
            int p4 = (tid & 15) * 4;
            floatx4 v = *reinterpret_cast<const floatx4*>(xb + (size_t)c * HW + pixbase + p4);
            int cs = p4 ^ (((c >> 3) & 7) << 2);
            *reinterpret_cast<floatx4*>(&tile[c][cs]) = v;
        }
        __syncthreads();
        __hip_bfloat16* xo = xt + ((size_t)b * HW + pixbase) * CC;
        int c8t = tid & 7;
        #pragma unroll
        for (int i = 0; i < 2; ++i) {
            int pixl = (tid >> 3) + i * 32;
            short8 o;
            #pragma unroll
            for (int j = 0; j < 8; ++j)
                o[j] = f2bfs(tile[c8t * 8 + j][pixl ^ (c8t << 2)]);
            *reinterpret_cast<short8*>(&xo[(size_t)pixl * CC + c8t * 8]) = o;
        }
        return;
    }
    int i = (blk - BB * 256) * 256 + tid;
    if (i < 18 * 4 * 64 * 8) {                 // wTf: 18 K-steps x 4 oc-tiles
        int jj = i & 7;
        int l  = (i >> 3) & 63;
        int nt = (i >> 9) & 3;
        int s  = i >> 11;
        int oc = nt * 16 + (l & 15);
        int kk = s * 32 + ((l >> 4) << 3) + jj;
        int c  = kk & 63;
        int kt = kk >> 6;
        wTf[i] = __float2bfloat16(w_dcn[(oc * CC + c) * 9 + kt]);
    }
    int j = i - 18 * 4 * 64 * 8;
    if (j >= 0 && j < 18 * 2 * 64 * 8) {       // wOf: 18 K-steps x 2 oc-tiles (27 used)
        int jj = j & 7;
        int l  = (j >> 3) & 63;
        int nt = (j >> 9) & 1;
        int s  = j >> 10;
        int oc = nt * 16 + (l & 15);
        int kk = s * 32 + ((l >> 4) << 3) + jj;
        int c  = kk & 63;
        int kt = kk >> 6;
        float v = 0.0f;
        if (oc < 18)      v = w_off[(oc * CC + c) * 9 + kt];
        else if (oc < 27) v = w_mask[((oc - 18) * CC + c) * 9 + kt];
        wOf[j] = __float2bfloat16(v);
    }
    int r = j - 18 * 2 * 64 * 8;
    if (r >= 0 && r < 27) rebias[r] = (r < 18) ? b_off[r] : b_mask[r - 18];
}

// ---------------- deform_fused: 64 px/block, XCD-swizzled -----------------------------
// NEW decomposition: wave = pixel-group (16 px), computes ALL oc.  A-fragments come
// from LDS once per step (own pg only); B-fragments loaded from global (coalesced,
// L1-broadcast across waves).  Bit-identical accumulation order.
// Phase A: 3x3 conv GEMM, raw-row LDS staging (= R12/R14).
// Phase B: tap setup from LDS bf16 offsets/mask.
// Phase C: gather, 3-deep pipeline + pk_fma COMBINE + MFMA.
__global__ __launch_bounds__(256, 4) void deform_fused(
    const __hip_bfloat16* __restrict__ xt,
    const __hip_bfloat16* __restrict__ wTf, const __hip_bfloat16* __restrict__ wOf,
    const float* __restrict__ rebias, const float* __restrict__ b_dcn,
    float* __restrict__ off_out, float* __restrict__ out)
{
    __shared__ __align__(16) char scr[64 * APAD * 2];         // 25600 B (A raw rows / C accs)
    __shared__ uintx4 tabs[KKN][64];                          // 9216 B
    __shared__ __hip_bfloat16 offs_l[18][68];                 // 2448 B
    __shared__ __hip_bfloat16 ms_l[KKN][68];                  // 1224 B

    int tid    = threadIdx.x;
    int lane   = tid & 63;
    int wv     = __builtin_amdgcn_readfirstlane(tid >> 6);    // wave = pixel-group
    int lane15 = lane & 15;
    int lq     = lane >> 4;       // 0..3
    int pix    = tid >> 3;        // 0..31 (gather pixel within half)
    int c8     = tid & 7;         // 0..7
    int co     = c8 * 16;         // byte offset within a pixel's 128B channel row
    int kreg   = lq << 3;

    // XCD-aware bijective swizzle (1024 blocks % 8 XCDs == 0)
    int bid = blockIdx.x;
    int swz = ((bid & 7) << 7) | (bid >> 3);
    int wo0 = (swz & 1) * 64;
    int row = (swz >> 1) & (HH - 1);
    int b   = swz >> 8;

    const char* xtb = (const char*)(xt + (size_t)b * HW * CC);
    const short8* wTf8 = (const short8*)wTf;
    const short8* wOf8 = (const short8*)wOf;
    const short8 zero8 = {0,0,0,0,0,0,0,0};

    // ================= Phase A: 3x3 conv GEMM, raw-row LDS staging ====================
    floatx4 accomA[2] = {{0,0,0,0},{0,0,0,0}};   // nt = 0,1 (all 32 oc, own pg)

#define STAGE_ROW(KY, SLOT) do { \
    int _y = row + (KY) - 1; \
    bool _yv = (unsigned)_y < (unsigned)HH; \
    int _yc = min(max(_y, 0), HH - 1); \
    _Pragma("unroll") \
    for (int _it = 0; _it < 3; ++_it) { \
        int _e = tid + _it * 256; \
        if (_e < 528) { \
            int _px66 = _e >> 3, _c8 = _e & 7; \
            int _xw = wo0 + _px66 - 1; \
            bool _v = _yv && ((unsigned)_xw < (unsigned)WW); \
            int _xc = min(max(_xw, 0), WW - 1); \
            short8 _t = *(const short8*)(xtb + (((_yc * WW) + _xc) << 7) + _c8 * 16); \
            if (!_v) _t = zero8; \
            *(short8*)(scr + (SLOT) * SLOTSZ + _px66 * RSTRIDE + _c8 * 16) = _t; \
        } \
    } \
} while (0)

#define AMFMA(KY, SLOT) do { \
    _Pragma("unroll") \
    for (int s6 = 0; s6 < 6; ++s6) { \
        int s = (KY) * 6 + s6; \
        int kx = s6 >> 1; \
        short8 a = *(const short8*)(scr + (SLOT) * SLOTSZ \
            + (wv * 16 + lane15 + kx) * RSTRIDE + (s6 & 1) * 64 + lq * 16); \
        short8 b0 = wOf8[(size_t)(s * 2 + 0) * 64 + lane]; \
        short8 b1 = wOf8[(size_t)(s * 2 + 1) * 64 + lane]; \
        accomA[0] = __builtin_amdgcn_mfma_f32_16x16x32_bf16(a, b0, accomA[0], 0, 0, 0); \
        accomA[1] = __builtin_amdgcn_mfma_f32_16x16x32_bf16(a, b1, accomA[1], 0, 0, 0); \
    } \
} while (0)

    STAGE_ROW(0, 0);
    __syncthreads();
    STAGE_ROW(1, 1);        // loads fly over chunk-0 MFMAs
    AMFMA(0, 0);
    __syncthreads();
    STAGE_ROW(2, 0);
    AMFMA(1, 1);
    __syncthreads();
    AMFMA(2, 0);

#undef STAGE_ROW
#undef AMFMA

    // epilogue A: own pg, all oc. offsets -> global (f32) + LDS bf16; mask -> LDS bf16
    {
        int pcl = wv * 16 + lq * 4;
        // nt = 0: oc = lane15 (0..15, all offset channels)
        float bias0 = rebias[lane15];
        floatx4 o0 = accomA[0];
        o0[0] += bias0; o0[1] += bias0; o0[2] += bias0; o0[3] += bias0;
        *reinterpret_cast<floatx4*>(
            &off_out[(((size_t)b * 18 + lane15) * HH + row) * WW + wo0 + pcl]) = o0;
        short4v ob0 = { f2bfs(o0[0]), f2bfs(o0[1]), f2bfs(o0[2]), f2bfs(o0[3]) };
        *reinterpret_cast<short4v*>(&offs_l[lane15][pcl]) = ob0;
        // nt = 1: oc = 16 + lane15 -> offsets 16,17 (lane15<2), mask 0..8 (2..10)
        int bi = min(16 + lane15, 26);
        float bias1 = rebias[bi];
        if (lane15 < 2) {
            floatx4 o1 = accomA[1];
            o1[0] += bias1; o1[1] += bias1; o1[2] += bias1; o1[3] += bias1;
            *reinterpret_cast<floatx4*>(
                &off_out[(((size_t)b * 18 + 16 + lane15) * HH + row) * WW + wo0 + pcl]) = o1;
            short4v ob1 = { f2bfs(o1[0]), f2bfs(o1[1]), f2bfs(o1[2]), f2bfs(o1[3]) };
            *reinterpret_cast<short4v*>(&offs_l[16 + lane15][pcl]) = ob1;
        } else if (lane15 < 11) {
            short4v mb;
            #pragma unroll
            for (int t = 0; t < 4; ++t)
                mb[t] = f2bfs(1.0f / (1.0f + expf(-(accomA[1][t] + bias1))));
            *reinterpret_cast<short4v*>(&ms_l[lane15 - 2][pcl]) = mb;
        }
    }
    __syncthreads();

    // ================= Phase B: bilinear tap setup (9 k x 64 px) =================
    for (int e = tid; e < KKN * 64; e += 256) {
        int k = e >> 6, p = e & 63;
        float dy = bf2f_us(*(const unsigned short*)&offs_l[2 * k][p]);
        float dx = bf2f_us(*(const unsigned short*)&offs_l[2 * k + 1][p]);
        float m  = bf2f_us(*(const unsigned short*)&ms_l[k][p]);
        float py = dy + (float)(k / 3) + (float)(row - 1);
        float px = dx + (float)(k % 3) + (float)(wo0 + p - 1);
        float y0f = floorf(py), x0f = floorf(px);
        float ly = py - y0f, lx = px - x0f;
        int y0 = (int)y0f, x0 = (int)x0f;
        uintx4 rec;
        #pragma unroll
        for (int t = 0; t < 4; ++t) {
            int yi = y0 + (t >> 1), xi = x0 + (t & 1);
            float wy = (t >> 1) ? ly : 1.0f - ly;
            float wx = (t & 1)  ? lx : 1.0f - lx;
            bool valid = ((unsigned)yi < (unsigned)HH) && ((unsigned)xi < (unsigned)WW);
            int yc2 = min(max(yi, 0), HH - 1);
            int xc2 = min(max(xi, 0), WW - 1);
            __hip_bfloat16 hw = __float2bfloat16(valid ? wy * wx * m : 0.0f);
            unsigned short wb = *reinterpret_cast<unsigned short*>(&hw);
            rec[t] = (unsigned)(yc2 * WW + xc2) | ((unsigned)wb << 16);
        }
        tabs[k][p] = rec;
    }
    __syncthreads();

    // ================= Phase C: gather (18 groups, 3-deep dbuf) + MFMA GEMM ==========
    short8 buf[3][4];
    uintx4 tb[3];
    floatx4 accv[4] = {{0,0,0,0},{0,0,0,0},{0,0,0,0},{0,0,0,0}};   // nt = 0..3

#define ACCS(PIX, COLB) (scr + (PIX) * (APAD * 2) + (COLB))

#define ISSUE(G) do { \
    uintx4 _t = tabs[(G) >> 1][pix + ((G) & 1) * 32]; \
    tb[(G) % 3] = _t; \
    buf[(G) % 3][0] = *(const short8*)(xtb + ((_t[0] & 0xffffu) << 7) + co); \
    buf[(G) % 3][1] = *(const short8*)(xtb + ((_t[1] & 0xffffu) << 7) + co); \
    buf[(G) % 3][2] = *(const short8*)(xtb + ((_t[2] & 0xffffu) << 7) + co); \
    buf[(G) % 3][3] = *(const short8*)(xtb + ((_t[3] & 0xffffu) << 7) + co); \
} while (0)

#define COMBINE(G) do { \
    floatx2 f2[4] = {{0,0},{0,0},{0,0},{0,0}}; \
    _Pragma("unroll") \
    for (int t = 0; t < 4; ++t) { \
        float wt = __uint_as_float(tb[(G) % 3][t] & 0xffff0000u); \
        floatx2 wt2 = {wt, wt}; \
        uintx4 dA = as_u4(buf[(G) % 3][t]); \
        _Pragma("unroll") \
        for (int jq = 0; jq < 4; ++jq) { \
            floatx2 xv = { blo(dA[jq]), bhi(dA[jq]) }; \
            f2[jq] = __builtin_elementwise_fma(wt2, xv, f2[jq]); \
        } \
    } \
    short8 oA; \
    _Pragma("unroll") \
    for (int jq = 0; jq < 4; ++jq) { \
        oA[2 * jq]     = f2bfs(f2[jq][0]); \
        oA[2 * jq + 1] = f2bfs(f2[jq][1]); \
    } \
    *(short8*)ACCS(((G) & 1) * 32 + pix, (((G) >> 1) % 3) * 128 + c8 * 16) = oA; \
} while (0)

#define CMFMA(CH) do { \
    _Pragma("unroll") \
    for (int step = 0; step < 6; ++step) { \
        int s = (CH) * 6 + step; \
        short8 a = *(const short8*)ACCS(wv * 16 + lane15, step * 64 + kreg * 2); \
        const short8* bp = wTf8 + (size_t)(s * 4) * 64 + lane; \
        accv[0] = __builtin_amdgcn_mfma_f32_16x16x32_bf16(a, bp[0],   accv[0], 0, 0, 0); \
        accv[1] = __builtin_amdgcn_mfma_f32_16x16x32_bf16(a, bp[64],  accv[1], 0, 0, 0); \
        accv[2] = __builtin_amdgcn_mfma_f32_16x16x32_bf16(a, bp[128], accv[2], 0, 0, 0); \
        accv[3] = __builtin_amdgcn_mfma_f32_16x16x32_bf16(a, bp[192], accv[3], 0, 0, 0); \
    } \
} while (0)

    ISSUE(0); ISSUE(1); ISSUE(2);
    COMBINE(0); ISSUE(3);
    COMBINE(1); ISSUE(4);
    COMBINE(2); ISSUE(5);
    COMBINE(3); ISSUE(6);           // groups 6..8 prefetched, fly across MFMA+barrier
    COMBINE(4); ISSUE(7);
    COMBINE(5); ISSUE(8);
    __syncthreads();
    CMFMA(0);
    asm volatile("s_waitcnt lgkmcnt(0)" ::: "memory");
    __builtin_amdgcn_s_barrier();   // raw: does NOT drain vmcnt
    COMBINE(6); ISSUE(9);
    COMBINE(7); ISSUE(10);
    COMBINE(8); ISSUE(11);
    COMBINE(9); ISSUE(12);
    COMBINE(10); ISSUE(13);
    COMBINE(11); ISSUE(14);
    __syncthreads();
    CMFMA(1);
    asm volatile("s_waitcnt lgkmcnt(0)" ::: "memory");
    __builtin_amdgcn_s_barrier();
    COMBINE(12); ISSUE(15);
    COMBINE(13); ISSUE(16);
    COMBINE(14); ISSUE(17);
    COMBINE(15); COMBINE(16); COMBINE(17);
    __syncthreads();
    CMFMA(2);

#undef ISSUE
#undef COMBINE
#undef CMFMA
#undef ACCS

    // epilogue C: own pg, all oc.  D: col=lane15 (oc), row=lq*4+reg (pixel)
    {
        int pcol = wo0 + wv * 16 + lq * 4;
        #pragma unroll
        for (int nt = 0; nt < 4; ++nt) {
            int oc = nt * 16 + lane15;
            float bias = b_dcn[oc];
            floatx4 o = accv[nt];
            o[0] += bias; o[1] += bias; o[2] += bias; o[3] += bias;
            *reinterpret_cast<floatx4*>(&out[(((size_t)b * OCN + oc) * HH + row) * WW + pcol]) = o;
        }
    }
}

extern "C" void kernel_launch(void* const* d_in, const int* in_sizes, int n_in,
                              void* d_out, int out_size, void* d_ws, size_t ws_size,
                              hipStream_t stream) {
    const float* x      = (const float*)d_in[0];
    const float* w_off  = (const float*)d_in[1];
    const float* b_off  = (const float*)d_in[2];
    const float* w_mask = (const float*)d_in[3];
    const float* b_mask = (const float*)d_in[4];
    const float* w_dcn  = (const float*)d_in[5];
    const float* b_dcn  = (const float*)d_in[6];

    float* out     = (float*)d_out;                       // B*OC*H*W
    float* off_out = out + (size_t)BB * OCN * HW;         // B*18*H*W (output 1)

    float* rebias  = (float*)d_ws;                        // 32 f32
    __hip_bfloat16* xt  = (__hip_bfloat16*)(rebias + 32); // B*HW*C bf16
    __hip_bfloat16* wTf = xt + (size_t)BB * HW * CC;      // 18*4*64*8 bf16
    __hip_bfloat16* wOf = wTf + 18 * 4 * 64 * 8;          // 18*2*64*8 bf16

    int prep_total  = 18 * 4 * 64 * 8 + 18 * 2 * 64 * 8 + 27;
    int prep_blocks = (prep_total + 255) / 256;           // 217
    transpose_prep<<<BB * 256 + prep_blocks, 256, 0, stream>>>(
        x, w_dcn, w_off, b_off, w_mask, b_mask, xt, wTf, wOf, rebias);

    deform_fused<<<BB * HH * 2, 256, 0, stream>>>(
        xt, wTf, wOf, rebias, b_dcn, off_out, out);
}

// Round 16
// 40.293 us; speedup vs baseline: 1.0539x; 1.0539x over previous
//
#include <hip/hip_runtime.h>
#include <hip/hip_bf16.h>
#include <math.h>

#define BB 4
#define CC 64
#define OCN 64
#define HH 128
#define WW 128
#define HW (HH*WW)
#define KKN 9
#define APAD 200          // accs row stride x2 bytes (400 B) for phase-C tile
#define RSTRIDE 144       // raw-row stride in bytes (64ch*2B + 16B pad)
#define SLOTSZ (66*RSTRIDE)  // 9504 B per raw-row slot

typedef short short8 __attribute__((ext_vector_type(8)));
typedef short short4v __attribute__((ext_vector_type(4)));
typedef float floatx4 __attribute__((ext_vector_type(4)));
typedef float floatx2 __attribute__((ext_vector_type(2)));
typedef float floatx16 __attribute__((ext_vector_type(16)));
typedef unsigned int uintx4 __attribute__((ext_vector_type(4)));

__device__ __forceinline__ float bf2f_us(unsigned short u) {
    return __uint_as_float(((unsigned)u) << 16);
}
__device__ __forceinline__ short f2bfs(float f) {
    __hip_bfloat16 h = __float2bfloat16(f);
    return *reinterpret_cast<short*>(&h);
}
__device__ __forceinline__ uintx4 as_u4(short8 v) {
    union { short8 s; uintx4 u; } x; x.s = v; return x.u;
}
__device__ __forceinline__ float blo(unsigned d) { return __uint_as_float(d << 16); }
__device__ __forceinline__ float bhi(unsigned d) { return __uint_as_float(d & 0xffff0000u); }

// ---------------- transpose_prep: xt transpose + weight fragment packing --------------
// wTf is now packed for mfma_f32_32x32x16_bf16: frag[((s16*2+nt)*64+l)*8+j] =
//   W[oc = nt*32+(l&31)][kk = s16*16 + (l>>5)*8 + j],  kk = tap*64 + c (tap-major).
// wOf unchanged (16x16 fragments for phase A).
__global__ __launch_bounds__(256) void transpose_prep(
    const float* __restrict__ x,
    const float* __restrict__ w_dcn, const float* __restrict__ w_off,
    const float* __restrict__ b_off, const float* __restrict__ w_mask,
    const float* __restrict__ b_mask,
    __hip_bfloat16* __restrict__ xt, __hip_bfloat16* __restrict__ wTf,
    __hip_bfloat16* __restrict__ wOf, float* __restrict__ rebias)
{
    int blk = blockIdx.x;
    int tid = threadIdx.x;
    if (blk < BB * 256) {
        __shared__ float tile[64][64];   // col = p ^ ((c>>3)<<2), 16 KB
        int pixbase = (blk & 255) * 64;
        int b       = blk >> 8;
        const float* xb = x + (size_t)b * CC * HW;
        #pragma unroll
        for (int i = 0; i < 4; ++i) {
            int c  = (tid >> 4) + i * 16;
            int p4 = (tid & 15) * 4;
            floatx4 v = *reinterpret_cast<const floatx4*>(xb + (size_t)c * HW + pixbase + p4);
            int cs = p4 ^ (((c >> 3) & 7) << 2);
            *reinterpret_cast<floatx4*>(&tile[c][cs]) = v;
        }
        __syncthreads();
        __hip_bfloat16* xo = xt + ((size_t)b * HW + pixbase) * CC;
        int c8t = tid & 7;
        #pragma unroll
        for (int i = 0; i < 2; ++i) {
            int pixl = (tid >> 3) + i * 32;
            short8 o;
            #pragma unroll
            for (int j = 0; j < 8; ++j)
                o[j] = f2bfs(tile[c8t * 8 + j][pixl ^ (c8t << 2)]);
            *reinterpret_cast<short8*>(&xo[(size_t)pixl * CC + c8t * 8]) = o;
        }
        return;
    }
    int i = (blk - BB * 256) * 256 + tid;
    if (i < 36 * 2 * 64 * 8) {                 // wTf: 36 K16-steps x 2 oc32-tiles
        int jj  = i & 7;
        int l   = (i >> 3) & 63;
        int nt  = (i >> 9) & 1;
        int s16 = i >> 10;
        int oc  = nt * 32 + (l & 31);
        int kk  = s16 * 16 + ((l >> 5) << 3) + jj;
        int c   = kk & 63;
        int kt  = kk >> 6;
        wTf[i] = __float2bfloat16(w_dcn[(oc * CC + c) * 9 + kt]);
    }
    int j = i - 36 * 2 * 64 * 8;
    if (j >= 0 && j < 18 * 2 * 64 * 8) {       // wOf: 18 K-steps x 2 oc-tiles (27 used)
        int jj = j & 7;
        int l  = (j >> 3) & 63;
        int nt = (j >> 9) & 1;
        int s  = j >> 10;
        int oc = nt * 16 + (l & 15);
        int kk = s * 32 + ((l >> 4) << 3) + jj;
        int c  = kk & 63;
        int kt = kk >> 6;
        float v = 0.0f;
        if (oc < 18)      v = w_off[(oc * CC + c) * 9 + kt];
        else if (oc < 27) v = w_mask[((oc - 18) * CC + c) * 9 + kt];
        wOf[j] = __float2bfloat16(v);
    }
    int r = j - 18 * 2 * 64 * 8;
    if (r >= 0 && r < 27) rebias[r] = (r < 18) ? b_off[r] : b_mask[r - 18];
}

// ---------------- deform_fused: 64 px/block, XCD-swizzled -----------------------------
// Phase A: 3x3 conv GEMM (16x16 MFMA), raw-row LDS staging (= R12/R14). Unchanged.
// Phase B: tap setup from LDS bf16 offsets/mask. Unchanged.
// Phase C: gather (3-deep pipeline, pk_fma) + 32x32x16 MFMA. Wave = one 32x32 tile
//          (ntw = wv&1 -> oc half, pxw = (wv>>1)*32 -> pixel half): 2x redundancy on
//          each operand instead of 4x on one.
__global__ __launch_bounds__(256, 4) void deform_fused(
    const __hip_bfloat16* __restrict__ xt,
    const __hip_bfloat16* __restrict__ wTf, const __hip_bfloat16* __restrict__ wOf,
    const float* __restrict__ rebias, const float* __restrict__ b_dcn,
    float* __restrict__ off_out, float* __restrict__ out)
{
    __shared__ __align__(16) char scr[64 * APAD * 2];         // 25600 B (A raw rows / C accs)
    __shared__ uintx4 tabs[KKN][64];                          // 9216 B
    __shared__ __hip_bfloat16 offs_l[18][68];                 // 2448 B
    __shared__ __hip_bfloat16 ms_l[KKN][68];                  // 1224 B

    int tid    = threadIdx.x;
    int lane   = tid & 63;
    int wv     = __builtin_amdgcn_readfirstlane(tid >> 6);
    int lane15 = lane & 15;
    int lq     = lane >> 4;       // 0..3
    int nt     = wv & 1;          // phase-A oc-tile
    int ph     = wv >> 1;         // phase-A pixel-half
    int pix    = tid >> 3;        // 0..31 (gather pixel within half)
    int c8     = tid & 7;         // 0..7
    int co     = c8 * 16;         // byte offset within a pixel's 128B channel row
    int kreg   = lq << 3;
    int l31    = lane & 31;       // phase-C: oc/pixel within 32-tile
    int kh     = lane >> 5;       // phase-C: k-half
    int ntw    = wv & 1;          // phase-C oc32 tile
    int pxw    = (wv >> 1) * 32;  // phase-C pixel base

    // XCD-aware bijective swizzle (1024 blocks % 8 XCDs == 0)
    int bid = blockIdx.x;
    int swz = ((bid & 7) << 7) | (bid >> 3);
    int wo0 = (swz & 1) * 64;
    int row = (swz >> 1) & (HH - 1);
    int b   = swz >> 8;

    const char* xtb = (const char*)(xt + (size_t)b * HW * CC);
    const short8* wTf8 = (const short8*)wTf;
    const short8* wOf8 = (const short8*)wOf;
    const short8 zero8 = {0,0,0,0,0,0,0,0};

    // ================= Phase A: 3x3 conv GEMM, raw-row LDS staging (= R14) ============
    floatx4 accomA[2] = {{0,0,0,0},{0,0,0,0}};

#define STAGE_ROW(KY, SLOT) do { \
    int _y = row + (KY) - 1; \
    bool _yv = (unsigned)_y < (unsigned)HH; \
    int _yc = min(max(_y, 0), HH - 1); \
    _Pragma("unroll") \
    for (int _it = 0; _it < 3; ++_it) { \
        int _e = tid + _it * 256; \
        if (_e < 528) { \
            int _px66 = _e >> 3, _c8 = _e & 7; \
            int _xw = wo0 + _px66 - 1; \
            bool _v = _yv && ((unsigned)_xw < (unsigned)WW); \
            int _xc = min(max(_xw, 0), WW - 1); \
            short8 _t = *(const short8*)(xtb + (((_yc * WW) + _xc) << 7) + _c8 * 16); \
            if (!_v) _t = zero8; \
            *(short8*)(scr + (SLOT) * SLOTSZ + _px66 * RSTRIDE + _c8 * 16) = _t; \
        } \
    } \
} while (0)

#define AMFMA(KY, SLOT) do { \
    _Pragma("unroll") \
    for (int s6 = 0; s6 < 6; ++s6) { \
        int s = (KY) * 6 + s6; \
        int kx = s6 >> 1; \
        short8 bfrag = wOf8[(size_t)(s * 2 + nt) * 64 + lane]; \
        _Pragma("unroll") \
        for (int q = 0; q < 2; ++q) { \
            int pg = ph * 2 + q; \
            short8 a = *(const short8*)(scr + (SLOT) * SLOTSZ \
                + (pg * 16 + lane15 + kx) * RSTRIDE + (s6 & 1) * 64 + lq * 16); \
            accomA[q] = __builtin_amdgcn_mfma_f32_16x16x32_bf16(a, bfrag, accomA[q], 0, 0, 0); \
        } \
    } \
} while (0)

    STAGE_ROW(0, 0);
    __syncthreads();
    STAGE_ROW(1, 1);        // loads fly over chunk-0 MFMAs
    AMFMA(0, 0);
    __syncthreads();
    STAGE_ROW(2, 0);
    AMFMA(1, 1);
    __syncthreads();
    AMFMA(2, 0);

#undef STAGE_ROW
#undef AMFMA

    // epilogue A: offsets -> global (f32) + LDS bf16; sigmoid(mask) -> LDS bf16
    #pragma unroll
    for (int q = 0; q < 2; ++q) {
        int pg = ph * 2 + q;
        int pcl = pg * 16 + lq * 4;
        int oc = nt * 16 + lane15;
        if (oc < 18) {
            float bias = rebias[oc];
            floatx4 o = accomA[q];
            o[0] += bias; o[1] += bias; o[2] += bias; o[3] += bias;
            *reinterpret_cast<floatx4*>(
                &off_out[(((size_t)b * 18 + oc) * HH + row) * WW + wo0 + pcl]) = o;
            short4v ob = { f2bfs(o[0]), f2bfs(o[1]), f2bfs(o[2]), f2bfs(o[3]) };
            *reinterpret_cast<short4v*>(&offs_l[oc][pcl]) = ob;
        } else if (oc < 27) {
            float bias = rebias[oc];
            short4v mb;
            #pragma unroll
            for (int t = 0; t < 4; ++t)
                mb[t] = f2bfs(1.0f / (1.0f + expf(-(accomA[q][t] + bias))));
            *reinterpret_cast<short4v*>(&ms_l[oc - 18][pcl]) = mb;
        }
    }
    __syncthreads();

    // ================= Phase B: bilinear tap setup (9 k x 64 px) =================
    for (int e = tid; e < KKN * 64; e += 256) {
        int k = e >> 6, p = e & 63;
        float dy = bf2f_us(*(const unsigned short*)&offs_l[2 * k][p]);
        float dx = bf2f_us(*(const unsigned short*)&offs_l[2 * k + 1][p]);
        float m  = bf2f_us(*(const unsigned short*)&ms_l[k][p]);
        float py = dy + (float)(k / 3) + (float)(row - 1);
        float px = dx + (float)(k % 3) + (float)(wo0 + p - 1);
        float y0f = floorf(py), x0f = floorf(px);
        float ly = py - y0f, lx = px - x0f;
        int y0 = (int)y0f, x0 = (int)x0f;
        uintx4 rec;
        #pragma unroll
        for (int t = 0; t < 4; ++t) {
            int yi = y0 + (t >> 1), xi = x0 + (t & 1);
            float wy = (t >> 1) ? ly : 1.0f - ly;
            float wx = (t & 1)  ? lx : 1.0f - lx;
            bool valid = ((unsigned)yi < (unsigned)HH) && ((unsigned)xi < (unsigned)WW);
            int yc2 = min(max(yi, 0), HH - 1);
            int xc2 = min(max(xi, 0), WW - 1);
            __hip_bfloat16 hw = __float2bfloat16(valid ? wy * wx * m : 0.0f);
            unsigned short wb = *reinterpret_cast<unsigned short*>(&hw);
            rec[t] = (unsigned)(yc2 * WW + xc2) | ((unsigned)wb << 16);
        }
        tabs[k][p] = rec;
    }
    __syncthreads();

    // ================= Phase C: gather (18 groups, 3-deep dbuf) + 32x32 MFMA ==========
    short8 buf[3][4];
    uintx4 tb[3];
    floatx16 acc = {0,0,0,0,0,0,0,0,0,0,0,0,0,0,0,0};

#define ACCS(PIX, COLB) (scr + (PIX) * (APAD * 2) + (COLB))

#define ISSUE(G) do { \
    uintx4 _t = tabs[(G) >> 1][pix + ((G) & 1) * 32]; \
    tb[(G) % 3] = _t; \
    buf[(G) % 3][0] = *(const short8*)(xtb + ((_t[0] & 0xffffu) << 7) + co); \
    buf[(G) % 3][1] = *(const short8*)(xtb + ((_t[1] & 0xffffu) << 7) + co); \
    buf[(G) % 3][2] = *(const short8*)(xtb + ((_t[2] & 0xffffu) << 7) + co); \
    buf[(G) % 3][3] = *(const short8*)(xtb + ((_t[3] & 0xffffu) << 7) + co); \
} while (0)

#define COMBINE(G) do { \
    floatx2 f2[4] = {{0,0},{0,0},{0,0},{0,0}}; \
    _Pragma("unroll") \
    for (int t = 0; t < 4; ++t) { \
        float wt = __uint_as_float(tb[(G) % 3][t] & 0xffff0000u); \
        floatx2 wt2 = {wt, wt}; \
        uintx4 dA = as_u4(buf[(G) % 3][t]); \
        _Pragma("unroll") \
        for (int jq = 0; jq < 4; ++jq) { \
            floatx2 xv = { blo(dA[jq]), bhi(dA[jq]) }; \
            f2[jq] = __builtin_elementwise_fma(wt2, xv, f2[jq]); \
        } \
    } \
    short8 oA; \
    _Pragma("unroll") \
    for (int jq = 0; jq < 4; ++jq) { \
        oA[2 * jq]     = f2bfs(f2[jq][0]); \
        oA[2 * jq + 1] = f2bfs(f2[jq][1]); \
    } \
    *(short8*)ACCS(((G) & 1) * 32 + pix, (((G) >> 1) % 3) * 128 + c8 * 16) = oA; \
} while (0)

// 12 K16-steps per chunk; A: row = pxw + l31, col bytes = s16*32 + kh*16 (kk*2).
#define CMFMA(CH) do { \
    _Pragma("unroll") \
    for (int s16 = 0; s16 < 12; ++s16) { \
        short8 a = *(const short8*)ACCS(pxw + l31, s16 * 32 + kh * 16); \
        short8 bfrag = wTf8[(size_t)(((CH) * 12 + s16) * 2 + ntw) * 64 + lane]; \
        acc = __builtin_amdgcn_mfma_f32_32x32x16_bf16(a, bfrag, acc, 0, 0, 0); \
    } \
} while (0)

    ISSUE(0); ISSUE(1); ISSUE(2);
    COMBINE(0); ISSUE(3);
    COMBINE(1); ISSUE(4);
    COMBINE(2); ISSUE(5);
    COMBINE(3); ISSUE(6);           // groups 6..8 prefetched, fly across MFMA+barrier
    COMBINE(4); ISSUE(7);
    COMBINE(5); ISSUE(8);
    __syncthreads();
    CMFMA(0);
    asm volatile("s_waitcnt lgkmcnt(0)" ::: "memory");
    __builtin_amdgcn_s_barrier();   // raw: does NOT drain vmcnt
    COMBINE(6); ISSUE(9);
    COMBINE(7); ISSUE(10);
    COMBINE(8); ISSUE(11);
    COMBINE(9); ISSUE(12);
    COMBINE(10); ISSUE(13);
    COMBINE(11); ISSUE(14);
    __syncthreads();
    CMFMA(1);
    asm volatile("s_waitcnt lgkmcnt(0)" ::: "memory");
    __builtin_amdgcn_s_barrier();
    COMBINE(12); ISSUE(15);
    COMBINE(13); ISSUE(16);
    COMBINE(14); ISSUE(17);
    COMBINE(15); COMBINE(16); COMBINE(17);
    __syncthreads();
    CMFMA(2);

#undef ISSUE
#undef COMBINE
#undef CMFMA
#undef ACCS

    // epilogue C: D layout col = l31 (oc within tile), row = (reg&3)+8*(reg>>2)+4*kh.
    {
        int oc = ntw * 32 + l31;
        float bias = b_dcn[oc];
        float* orow = &out[(((size_t)b * OCN + oc) * HH + row) * WW];
        #pragma unroll
        for (int q = 0; q < 4; ++q) {
            floatx4 o = { acc[4 * q] + bias, acc[4 * q + 1] + bias,
                          acc[4 * q + 2] + bias, acc[4 * q + 3] + bias };
            int px0 = wo0 + pxw + 8 * q + 4 * kh;
            *reinterpret_cast<floatx4*>(orow + px0) = o;
        }
    }
}

extern "C" void kernel_launch(void* const* d_in, const int* in_sizes, int n_in,
                              void* d_out, int out_size, void* d_ws, size_t ws_size,
                              hipStream_t stream) {
    const float* x      = (const float*)d_in[0];
    const float* w_off  = (const float*)d_in[1];
    const float* b_off  = (const float*)d_in[2];
    const float* w_mask = (const float*)d_in[3];
    const float* b_mask = (const float*)d_in[4];
    const float* w_dcn  = (const float*)d_in[5];
    const float* b_dcn  = (const float*)d_in[6];

    float* out     = (float*)d_out;                       // B*OC*H*W
    float* off_out = out + (size_t)BB * OCN * HW;         // B*18*H*W (output 1)

    float* rebias  = (float*)d_ws;                        // 32 f32
    __hip_bfloat16* xt  = (__hip_bfloat16*)(rebias + 32); // B*HW*C bf16
    __hip_bfloat16* wTf = xt + (size_t)BB * HW * CC;      // 36*2*64*8 bf16
    __hip_bfloat16* wOf = wTf + 36 * 2 * 64 * 8;          // 18*2*64*8 bf16

    int prep_total  = 36 * 2 * 64 * 8 + 18 * 2 * 64 * 8 + 27;
    int prep_blocks = (prep_total + 255) / 256;           // 217
    transpose_prep<<<BB * 256 + prep_blocks, 256, 0, stream>>>(
        x, w_dcn, w_off, b_off, w_mask, b_mask, xt, wTf, wOf, rebias);

    deform_fused<<<BB * HH * 2, 256, 0, stream>>>(
        xt, wTf, wOf, rebias, b_dcn, off_out, out);
}

// Round 17
// 38.200 us; speedup vs baseline: 1.1117x; 1.0548x over previous
//
#include <hip/hip_runtime.h>
#include <hip/hip_bf16.h>
#include <math.h>

#define BB 4
#define CC 64
#define OCN 64
#define HH 128
#define WW 128
#define HW (HH*WW)
#define KKN 9
#define APAD 200          // accs row stride x2 bytes (400 B) for phase-C tile
#define RSTRIDE 144       // raw-row stride in bytes (64ch*2B + 16B pad)
#define SLOTSZ (66*RSTRIDE)  // 9504 B per raw-row slot

typedef short short8 __attribute__((ext_vector_type(8)));
typedef short short4v __attribute__((ext_vector_type(4)));
typedef float floatx4 __attribute__((ext_vector_type(4)));
typedef float floatx2 __attribute__((ext_vector_type(2)));
typedef unsigned int uintx4 __attribute__((ext_vector_type(4)));

__device__ __forceinline__ float bf2f_us(unsigned short u) {
    return __uint_as_float(((unsigned)u) << 16);
}
__device__ __forceinline__ short f2bfs(float f) {
    __hip_bfloat16 h = __float2bfloat16(f);
    return *reinterpret_cast<short*>(&h);
}
__device__ __forceinline__ uintx4 as_u4(short8 v) {
    union { short8 s; uintx4 u; } x; x.s = v; return x.u;
}
__device__ __forceinline__ float blo(unsigned d) { return __uint_as_float(d << 16); }
__device__ __forceinline__ float bhi(unsigned d) { return __uint_as_float(d & 0xffff0000u); }

// ---------------- transpose_prep: float4 loads, 64 px/block, XOR-swizzled tile --------
__global__ __launch_bounds__(256) void transpose_prep(
    const float* __restrict__ x,
    const float* __restrict__ w_dcn, const float* __restrict__ w_off,
    const float* __restrict__ b_off, const float* __restrict__ w_mask,
    const float* __restrict__ b_mask,
    __hip_bfloat16* __restrict__ xt, __hip_bfloat16* __restrict__ wTf,
    __hip_bfloat16* __restrict__ wOf, float* __restrict__ rebias)
{
    int blk = blockIdx.x;
    int tid = threadIdx.x;
    if (blk < BB * 256) {
        __shared__ float tile[64][64];   // col = p ^ ((c>>3)<<2), 16 KB
        int pixbase = (blk & 255) * 64;
        int b       = blk >> 8;
        const float* xb = x + (size_t)b * CC * HW;
        #pragma unroll
        for (int i = 0; i < 4; ++i) {
            int c  = (tid >> 4) + i * 16;
            int p4 = (tid & 15) * 4;
            floatx4 v = *reinterpret_cast<const floatx4*>(xb + (size_t)c * HW + pixbase + p4);
            int cs = p4 ^ (((c >> 3) & 7) << 2);
            *reinterpret_cast<floatx4*>(&tile[c][cs]) = v;
        }
        __syncthreads();
        __hip_bfloat16* xo = xt + ((size_t)b * HW + pixbase) * CC;
        int c8t = tid & 7;
        #pragma unroll
        for (int i = 0; i < 2; ++i) {
            int pixl = (tid >> 3) + i * 32;
            short8 o;
            #pragma unroll
            for (int j = 0; j < 8; ++j)
                o[j] = f2bfs(tile[c8t * 8 + j][pixl ^ (c8t << 2)]);
            *reinterpret_cast<short8*>(&xo[(size_t)pixl * CC + c8t * 8]) = o;
        }
        return;
    }
    int i = (blk - BB * 256) * 256 + tid;
    if (i < 18 * 4 * 64 * 8) {                 // wTf: 18 K-steps x 4 oc-tiles
        int jj = i & 7;
        int l  = (i >> 3) & 63;
        int nt = (i >> 9) & 3;
        int s  = i >> 11;
        int oc = nt * 16 + (l & 15);
        int kk = s * 32 + ((l >> 4) << 3) + jj;
        int c  = kk & 63;
        int kt = kk >> 6;
        wTf[i] = __float2bfloat16(w_dcn[(oc * CC + c) * 9 + kt]);
    }
    int j = i - 18 * 4 * 64 * 8;
    if (j >= 0 && j < 18 * 2 * 64 * 8) {       // wOf: 18 K-steps x 2 oc-tiles (27 used)
        int jj = j & 7;
        int l  = (j >> 3) & 63;
        int nt = (j >> 9) & 1;
        int s  = j >> 10;
        int oc = nt * 16 + (l & 15);
        int kk = s * 32 + ((l >> 4) << 3) + jj;
        int c  = kk & 63;
        int kt = kk >> 6;
        float v = 0.0f;
        if (oc < 18)      v = w_off[(oc * CC + c) * 9 + kt];
        else if (oc < 27) v = w_mask[((oc - 18) * CC + c) * 9 + kt];
        wOf[j] = __float2bfloat16(v);
    }
    int r = j - 18 * 2 * 64 * 8;
    if (r >= 0 && r < 27) rebias[r] = (r < 18) ? b_off[r] : b_mask[r - 18];
}

// ---------------- deform_fused: 64 px/block, XCD-swizzled (= R14 + setprio) -----------
// Phase A: 3x3 conv GEMM; halo rows staged ONCE as [66][64ch] LDS slots (coalesced
//          8 lanes/line), A-frags read shifted. wave = (nt, ph).
// Phase B: tap setup from LDS bf16 offsets/mask.
// Phase C: gather, 3-deep pipeline + pk_fma COMBINE + MFMA (wave = oc-tile, 4 pgs,
//          4 independent acc chains). s_setprio(1) wraps MFMA clusters (T5).
__global__ __launch_bounds__(256, 4) void deform_fused(
    const __hip_bfloat16* __restrict__ xt,
    const __hip_bfloat16* __restrict__ wTf, const __hip_bfloat16* __restrict__ wOf,
    const float* __restrict__ rebias, const float* __restrict__ b_dcn,
    float* __restrict__ off_out, float* __restrict__ out)
{
    __shared__ __align__(16) char scr[64 * APAD * 2];         // 25600 B (A raw rows / C accs)
    __shared__ uintx4 tabs[KKN][64];                          // 9216 B
    __shared__ __hip_bfloat16 offs_l[18][68];                 // 2448 B
    __shared__ __hip_bfloat16 ms_l[KKN][68];                  // 1224 B

    int tid    = threadIdx.x;
    int lane   = tid & 63;
    int wv     = __builtin_amdgcn_readfirstlane(tid >> 6);
    int lane15 = lane & 15;
    int lq     = lane >> 4;       // 0..3
    int nt     = wv & 1;          // phase-A oc-tile
    int ph     = wv >> 1;         // phase-A pixel-half
    int pix    = tid >> 3;        // 0..31 (gather pixel within half)
    int c8     = tid & 7;         // 0..7
    int co     = c8 * 16;         // byte offset within a pixel's 128B channel row
    int kreg   = lq << 3;

    // XCD-aware bijective swizzle (1024 blocks % 8 XCDs == 0)
    int bid = blockIdx.x;
    int swz = ((bid & 7) << 7) | (bid >> 3);
    int wo0 = (swz & 1) * 64;
    int row = (swz >> 1) & (HH - 1);
    int b   = swz >> 8;

    const char* xtb = (const char*)(xt + (size_t)b * HW * CC);
    const short8* wTf8 = (const short8*)wTf;
    const short8* wOf8 = (const short8*)wOf;
    const short8 zero8 = {0,0,0,0,0,0,0,0};

    // ================= Phase A: 3x3 conv GEMM, raw-row LDS staging ====================
    floatx4 accomA[2] = {{0,0,0,0},{0,0,0,0}};

#define STAGE_ROW(KY, SLOT) do { \
    int _y = row + (KY) - 1; \
    bool _yv = (unsigned)_y < (unsigned)HH; \
    int _yc = min(max(_y, 0), HH - 1); \
    _Pragma("unroll") \
    for (int _it = 0; _it < 3; ++_it) { \
        int _e = tid + _it * 256; \
        if (_e < 528) { \
            int _px66 = _e >> 3, _c8 = _e & 7; \
            int _xw = wo0 + _px66 - 1; \
            bool _v = _yv && ((unsigned)_xw < (unsigned)WW); \
            int _xc = min(max(_xw, 0), WW - 1); \
            short8 _t = *(const short8*)(xtb + (((_yc * WW) + _xc) << 7) + _c8 * 16); \
            if (!_v) _t = zero8; \
            *(short8*)(scr + (SLOT) * SLOTSZ + _px66 * RSTRIDE + _c8 * 16) = _t; \
        } \
    } \
} while (0)

#define AMFMA(KY, SLOT) do { \
    __builtin_amdgcn_s_setprio(1); \
    _Pragma("unroll") \
    for (int s6 = 0; s6 < 6; ++s6) { \
        int s = (KY) * 6 + s6; \
        int kx = s6 >> 1; \
        short8 bfrag = wOf8[(size_t)(s * 2 + nt) * 64 + lane]; \
        _Pragma("unroll") \
        for (int q = 0; q < 2; ++q) { \
            int pg = ph * 2 + q; \
            short8 a = *(const short8*)(scr + (SLOT) * SLOTSZ \
                + (pg * 16 + lane15 + kx) * RSTRIDE + (s6 & 1) * 64 + lq * 16); \
            accomA[q] = __builtin_amdgcn_mfma_f32_16x16x32_bf16(a, bfrag, accomA[q], 0, 0, 0); \
        } \
    } \
    __builtin_amdgcn_s_setprio(0); \
} while (0)

    STAGE_ROW(0, 0);
    __syncthreads();
    STAGE_ROW(1, 1);        // loads fly over chunk-0 MFMAs
    AMFMA(0, 0);
    __syncthreads();
    STAGE_ROW(2, 0);
    AMFMA(1, 1);
    __syncthreads();
    AMFMA(2, 0);

#undef STAGE_ROW
#undef AMFMA

    // epilogue A: offsets -> global (f32) + LDS bf16; sigmoid(mask) -> LDS bf16
    #pragma unroll
    for (int q = 0; q < 2; ++q) {
        int pg = ph * 2 + q;
        int pcl = pg * 16 + lq * 4;
        int oc = nt * 16 + lane15;
        if (oc < 18) {
            float bias = rebias[oc];
            floatx4 o = accomA[q];
            o[0] += bias; o[1] += bias; o[2] += bias; o[3] += bias;
            *reinterpret_cast<floatx4*>(
                &off_out[(((size_t)b * 18 + oc) * HH + row) * WW + wo0 + pcl]) = o;
            short4v ob = { f2bfs(o[0]), f2bfs(o[1]), f2bfs(o[2]), f2bfs(o[3]) };
            *reinterpret_cast<short4v*>(&offs_l[oc][pcl]) = ob;
        } else if (oc < 27) {
            float bias = rebias[oc];
            short4v mb;
            #pragma unroll
            for (int t = 0; t < 4; ++t)
                mb[t] = f2bfs(1.0f / (1.0f + expf(-(accomA[q][t] + bias))));
            *reinterpret_cast<short4v*>(&ms_l[oc - 18][pcl]) = mb;
        }
    }
    __syncthreads();

    // ================= Phase B: bilinear tap setup (9 k x 64 px) =================
    for (int e = tid; e < KKN * 64; e += 256) {
        int k = e >> 6, p = e & 63;
        float dy = bf2f_us(*(const unsigned short*)&offs_l[2 * k][p]);
        float dx = bf2f_us(*(const unsigned short*)&offs_l[2 * k + 1][p]);
        float m  = bf2f_us(*(const unsigned short*)&ms_l[k][p]);
        float py = dy + (float)(k / 3) + (float)(row - 1);
        float px = dx + (float)(k % 3) + (float)(wo0 + p - 1);
        float y0f = floorf(py), x0f = floorf(px);
        float ly = py - y0f, lx = px - x0f;
        int y0 = (int)y0f, x0 = (int)x0f;
        uintx4 rec;
        #pragma unroll
        for (int t = 0; t < 4; ++t) {
            int yi = y0 + (t >> 1), xi = x0 + (t & 1);
            float wy = (t >> 1) ? ly : 1.0f - ly;
            float wx = (t & 1)  ? lx : 1.0f - lx;
            bool valid = ((unsigned)yi < (unsigned)HH) && ((unsigned)xi < (unsigned)WW);
            int yc2 = min(max(yi, 0), HH - 1);
            int xc2 = min(max(xi, 0), WW - 1);
            __hip_bfloat16 hw = __float2bfloat16(valid ? wy * wx * m : 0.0f);
            unsigned short wb = *reinterpret_cast<unsigned short*>(&hw);
            rec[t] = (unsigned)(yc2 * WW + xc2) | ((unsigned)wb << 16);
        }
        tabs[k][p] = rec;
    }
    __syncthreads();

    // ================= Phase C: gather (18 groups, 3-deep dbuf) + MFMA GEMM ==========
    short8 buf[3][4];
    uintx4 tb[3];
    floatx4 accv[4] = {{0,0,0,0},{0,0,0,0},{0,0,0,0},{0,0,0,0}};

#define ACCS(PIX, COLB) (scr + (PIX) * (APAD * 2) + (COLB))

#define ISSUE(G) do { \
    uintx4 _t = tabs[(G) >> 1][pix + ((G) & 1) * 32]; \
    tb[(G) % 3] = _t; \
    buf[(G) % 3][0] = *(const short8*)(xtb + ((_t[0] & 0xffffu) << 7) + co); \
    buf[(G) % 3][1] = *(const short8*)(xtb + ((_t[1] & 0xffffu) << 7) + co); \
    buf[(G) % 3][2] = *(const short8*)(xtb + ((_t[2] & 0xffffu) << 7) + co); \
    buf[(G) % 3][3] = *(const short8*)(xtb + ((_t[3] & 0xffffu) << 7) + co); \
} while (0)

#define COMBINE(G) do { \
    floatx2 f2[4] = {{0,0},{0,0},{0,0},{0,0}}; \
    _Pragma("unroll") \
    for (int t = 0; t < 4; ++t) { \
        float wt = __uint_as_float(tb[(G) % 3][t] & 0xffff0000u); \
        floatx2 wt2 = {wt, wt}; \
        uintx4 dA = as_u4(buf[(G) % 3][t]); \
        _Pragma("unroll") \
        for (int jq = 0; jq < 4; ++jq) { \
            floatx2 xv = { blo(dA[jq]), bhi(dA[jq]) }; \
            f2[jq] = __builtin_elementwise_fma(wt2, xv, f2[jq]); \
        } \
    } \
    short8 oA; \
    _Pragma("unroll") \
    for (int jq = 0; jq < 4; ++jq) { \
        oA[2 * jq]     = f2bfs(f2[jq][0]); \
        oA[2 * jq + 1] = f2bfs(f2[jq][1]); \
    } \
    *(short8*)ACCS(((G) & 1) * 32 + pix, (((G) >> 1) % 3) * 128 + c8 * 16) = oA; \
} while (0)

#define CMFMA(CH) do { \
    __builtin_amdgcn_s_setprio(1); \
    _Pragma("unroll") \
    for (int step = 0; step < 6; ++step) { \
        int s = (CH) * 6 + step; \
        short8 bfrag = wTf8[(size_t)(s * 4 + wv) * 64 + lane]; \
        _Pragma("unroll") \
        for (int pg = 0; pg < 4; ++pg) { \
            short8 a = *(const short8*)ACCS(pg * 16 + lane15, step * 64 + kreg * 2); \
            accv[pg] = __builtin_amdgcn_mfma_f32_16x16x32_bf16(a, bfrag, accv[pg], 0, 0, 0); \
        } \
    } \
    __builtin_amdgcn_s_setprio(0); \
} while (0)

    ISSUE(0); ISSUE(1); ISSUE(2);
    COMBINE(0); ISSUE(3);
    COMBINE(1); ISSUE(4);
    COMBINE(2); ISSUE(5);
    COMBINE(3); ISSUE(6);           // groups 6..8 prefetched, fly across MFMA+barrier
    COMBINE(4); ISSUE(7);
    COMBINE(5); ISSUE(8);
    __syncthreads();
    CMFMA(0);
    asm volatile("s_waitcnt lgkmcnt(0)" ::: "memory");
    __builtin_amdgcn_s_barrier();   // raw: does NOT drain vmcnt
    COMBINE(6); ISSUE(9);
    COMBINE(7); ISSUE(10);
    COMBINE(8); ISSUE(11);
    COMBINE(9); ISSUE(12);
    COMBINE(10); ISSUE(13);
    COMBINE(11); ISSUE(14);
    __syncthreads();
    CMFMA(1);
    asm volatile("s_waitcnt lgkmcnt(0)" ::: "memory");
    __builtin_amdgcn_s_barrier();
    COMBINE(12); ISSUE(15);
    COMBINE(13); ISSUE(16);
    COMBINE(14); ISSUE(17);
    COMBINE(15); COMBINE(16); COMBINE(17);
    __syncthreads();
    CMFMA(2);

#undef ISSUE
#undef COMBINE
#undef CMFMA
#undef ACCS

    // epilogue C: wave wv owns oc-tile wv; D: col=lane15 (oc), row=lq*4+reg (pixel)
    {
        int oc = wv * 16 + lane15;
        float bias = b_dcn[oc];
        #pragma unroll
        for (int pg = 0; pg < 4; ++pg) {
            int pcol = wo0 + pg * 16 + lq * 4;
            floatx4 o = accv[pg];
            o[0] += bias; o[1] += bias; o[2] += bias; o[3] += bias;
            *reinterpret_cast<floatx4*>(&out[(((size_t)b * OCN + oc) * HH + row) * WW + pcol]) = o;
        }
    }
}

extern "C" void kernel_launch(void* const* d_in, const int* in_sizes, int n_in,
                              void* d_out, int out_size, void* d_ws, size_t ws_size,
                              hipStream_t stream) {
    const float* x      = (const float*)d_in[0];
    const float* w_off  = (const float*)d_in[1];
    const float* b_off  = (const float*)d_in[2];
    const float* w_mask = (const float*)d_in[3];
    const float* b_mask = (const float*)d_in[4];
    const float* w_dcn  = (const float*)d_in[5];
    const float* b_dcn  = (const float*)d_in[6];

    float* out     = (float*)d_out;                       // B*OC*H*W
    float* off_out = out + (size_t)BB * OCN * HW;         // B*18*H*W (output 1)

    float* rebias  = (float*)d_ws;                        // 32 f32
    __hip_bfloat16* xt  = (__hip_bfloat16*)(rebias + 32); // B*HW*C bf16
    __hip_bfloat16* wTf = xt + (size_t)BB * HW * CC;      // 18*4*64*8 bf16
    __hip_bfloat16* wOf = wTf + 18 * 4 * 64 * 8;          // 18*2*64*8 bf16

    int prep_total  = 18 * 4 * 64 * 8 + 18 * 2 * 64 * 8 + 27;
    int prep_blocks = (prep_total + 255) / 256;           // 217
    transpose_prep<<<BB * 256 + prep_blocks, 256, 0, stream>>>(
        x, w_dcn, w_off, b_off, w_mask, b_mask, xt, wTf, wOf, rebias);

    deform_fused<<<BB * HH * 2, 256, 0, stream>>>(
        xt, wTf, wOf, rebias, b_dcn, off_out, out);
}